// Round 1
// baseline (5997.257 us; speedup 1.0000x reference)
//
#include <hip/hip_runtime.h>

#define NN 50000
#define NE 800000
#define NG 128
#define NL 3

__device__ __forceinline__ float rdl(float v, int l) {
  return __int_as_float(__builtin_amdgcn_readlane(__float_as_int(v), l));
}
__device__ __forceinline__ float silu_f(float x) {
  return x / (1.f + __expf(-x));
}
__device__ __forceinline__ float wave_sum(float v) {
#pragma unroll
  for (int m = 1; m < 64; m <<= 1) v += __shfl_xor(v, m, 64);
  return v;
}

// ---------------- init / small kernels ----------------
__global__ __launch_bounds__(256) void k_init_h(const int* __restrict__ nt,
                                                const float* __restrict__ emb,
                                                float* __restrict__ h) {
  int idx = blockIdx.x * 256 + threadIdx.x;
  if (idx < NN * 64) h[idx] = emb[nt[idx >> 6] * 64 + (idx & 63)];
}

__global__ __launch_bounds__(256) void k_prep(const float* __restrict__ pos_in,
                                              float* __restrict__ pos,
                                              float* __restrict__ deg,
                                              float* __restrict__ g,
                                              float* __restrict__ gcnt) {
  int idx = blockIdx.x * 256 + threadIdx.x;
  if (idx < NN * 3) pos[idx] = pos_in[idx];
  if (idx < NN) deg[idx] = 0.f;
  if (idx < NG * 64) g[idx] = 0.f;
  if (idx < NG) gcnt[idx] = 0.f;
}

__global__ __launch_bounds__(256) void k_hist(const int* __restrict__ ei,
                                              float* __restrict__ deg) {
  int e = blockIdx.x * 256 + threadIdx.x;
  if (e < NE) atomicAdd(&deg[ei[NE + e]], 1.f);
}

__global__ __launch_bounds__(256) void k_cnt(const int* __restrict__ batch,
                                             float* __restrict__ deg,
                                             float* __restrict__ gcnt) {
  int i = blockIdx.x * 256 + threadIdx.x;
  if (i < NN) {
    deg[i] = fmaxf(deg[i], 1.f);
    atomicAdd(&gcnt[batch[i]], 1.f);
  }
}

__global__ __launch_bounds__(256) void k_zero(float* __restrict__ agg,
                                              float* __restrict__ posd) {
  int idx = blockIdx.x * 256 + threadIdx.x;
  if (idx < NN * 64) agg[idx] = 0.f;
  else if (idx < NN * 64 + NN * 3) posd[idx - NN * 64] = 0.f;
}

__global__ __launch_bounds__(256) void k_pos(float* __restrict__ pos,
                                             const float* __restrict__ posd,
                                             const float* __restrict__ deg) {
  int idx = blockIdx.x * 256 + threadIdx.x;
  if (idx < NN * 3) pos[idx] += posd[idx] / deg[idx / 3];
}

__global__ __launch_bounds__(256) void k_pool(const float* __restrict__ h,
                                              const int* __restrict__ batch,
                                              float* __restrict__ g) {
  int idx = blockIdx.x * 256 + threadIdx.x;
  if (idx < NN * 64) atomicAdd(&g[batch[idx >> 6] * 64 + (idx & 63)], h[idx]);
}

// ---------------- edge message kernel ----------------
__global__ __launch_bounds__(256) void k_edge(
    const float* __restrict__ h, const float* __restrict__ pos,
    const int* __restrict__ ei, const float* __restrict__ eattr,
    const float* __restrict__ W1, const float* __restrict__ B1,
    const float* __restrict__ W2, const float* __restrict__ B2,
    const float* __restrict__ C1, const float* __restrict__ CB1,
    const float* __restrict__ C2, const float* __restrict__ CB2,
    float* __restrict__ agg, float* __restrict__ posd) {
  __shared__ float sW1[133 * 64];
  __shared__ float sW2[64 * 64];
  for (int i = threadIdx.x; i < 133 * 64; i += 256) sW1[i] = W1[i];
  for (int i = threadIdx.x; i < 64 * 64; i += 256) sW2[i] = W2[i];
  __syncthreads();
  const int lane = threadIdx.x & 63;
  const float eb1 = B1[lane], eb2 = B2[lane], cb1 = CB1[lane];
  const float cw2 = C2[lane], cb2 = CB2[0];
  const int wid = (blockIdx.x * 256 + threadIdx.x) >> 6;
  const int nw = (gridDim.x * 256) >> 6;
  for (int quad = wid; quad < NE / 4; quad += nw) {
    const int e0 = quad * 4;
    int dst[4];
    float hd[4], hs[4], rx[4], ry[4], rz[4], d2[4], ea[4][4];
#pragma unroll
    for (int i = 0; i < 4; ++i) {
      const int e = e0 + i;
      const int s = ei[e];
      const int d = ei[NE + e];
      dst[i] = d;
      hd[i] = h[d * 64 + lane];
      hs[i] = h[s * 64 + lane];
      rx[i] = pos[d * 3 + 0] - pos[s * 3 + 0];
      ry[i] = pos[d * 3 + 1] - pos[s * 3 + 1];
      rz[i] = pos[d * 3 + 2] - pos[s * 3 + 2];
      d2[i] = rx[i] * rx[i] + ry[i] * ry[i] + rz[i] * rz[i];
#pragma unroll
      for (int c = 0; c < 4; ++c) ea[i][c] = eattr[e * 4 + c];
    }
    // GEMV1: 133 -> 64   (m_in = [h[dst], h[src], d2, edge_attr])
    float a1[4] = {eb1, eb1, eb1, eb1};
#pragma unroll
    for (int k = 0; k < 64; ++k) {
      const float w = sW1[k * 64 + lane];
#pragma unroll
      for (int i = 0; i < 4; ++i) a1[i] += rdl(hd[i], k) * w;
    }
#pragma unroll
    for (int k = 0; k < 64; ++k) {
      const float w = sW1[(64 + k) * 64 + lane];
#pragma unroll
      for (int i = 0; i < 4; ++i) a1[i] += rdl(hs[i], k) * w;
    }
    {
      const float wd = sW1[128 * 64 + lane];
#pragma unroll
      for (int i = 0; i < 4; ++i) a1[i] += d2[i] * wd;
#pragma unroll
      for (int c = 0; c < 4; ++c) {
        const float w = sW1[(129 + c) * 64 + lane];
#pragma unroll
        for (int i = 0; i < 4; ++i) a1[i] += ea[i][c] * w;
      }
    }
    float m1[4];
#pragma unroll
    for (int i = 0; i < 4; ++i) m1[i] = silu_f(a1[i]);
    // GEMV2: 64 -> 64
    float a2[4] = {eb2, eb2, eb2, eb2};
#pragma unroll
    for (int k = 0; k < 64; ++k) {
      const float w = sW2[k * 64 + lane];
#pragma unroll
      for (int i = 0; i < 4; ++i) a2[i] += rdl(m1[i], k) * w;
    }
    float mm[4];
#pragma unroll
    for (int i = 0; i < 4; ++i) mm[i] = silu_f(a2[i]);
    // coord MLP: 64 -> 64 (silu) -> 1
    float a3[4] = {cb1, cb1, cb1, cb1};
#pragma unroll
    for (int k = 0; k < 64; ++k) {
      const float w = C1[k * 64 + lane];  // global, L1-resident (16 KB)
#pragma unroll
      for (int i = 0; i < 4; ++i) a3[i] += rdl(mm[i], k) * w;
    }
#pragma unroll
    for (int i = 0; i < 4; ++i) {
      const float cv = wave_sum(silu_f(a3[i]) * cw2) + cb2;
      atomicAdd(&agg[dst[i] * 64 + lane], mm[i]);
      if (lane == 0) {
        atomicAdd(&posd[dst[i] * 3 + 0], rx[i] * cv);
        atomicAdd(&posd[dst[i] * 3 + 1], ry[i] * cv);
        atomicAdd(&posd[dst[i] * 3 + 2], rz[i] * cv);
      }
    }
  }
}

// ---------------- node update kernel ----------------
__global__ __launch_bounds__(256) void k_node(
    float* __restrict__ h, const float* __restrict__ agg,
    const float* __restrict__ W1, const float* __restrict__ B1,
    const float* __restrict__ W2, const float* __restrict__ B2) {
  __shared__ float sW1[128 * 64];
  __shared__ float sW2[64 * 64];
  for (int i = threadIdx.x; i < 128 * 64; i += 256) sW1[i] = W1[i];
  for (int i = threadIdx.x; i < 64 * 64; i += 256) sW2[i] = W2[i];
  __syncthreads();
  const int lane = threadIdx.x & 63;
  const float nb1 = B1[lane], nb2 = B2[lane];
  const int wid = (blockIdx.x * 256 + threadIdx.x) >> 6;
  const int nw = (gridDim.x * 256) >> 6;
  for (int n = wid; n < NN; n += nw) {
    const float hj = h[n * 64 + lane];
    const float aj = agg[n * 64 + lane];
    float a1 = nb1;
#pragma unroll
    for (int k = 0; k < 64; ++k) a1 += rdl(hj, k) * sW1[k * 64 + lane];
#pragma unroll
    for (int k = 0; k < 64; ++k) a1 += rdl(aj, k) * sW1[(64 + k) * 64 + lane];
    const float u = silu_f(a1);
    float a2 = nb2;
#pragma unroll
    for (int k = 0; k < 64; ++k) a2 += rdl(u, k) * sW2[k * 64 + lane];
    h[n * 64 + lane] = hj + a2;
  }
}

// ---------------- pooled head: q-circuit + MLP ----------------
__global__ __launch_bounds__(256) void k_final(
    const float* __restrict__ g, const float* __restrict__ gcnt,
    const float* __restrict__ prew, const float* __restrict__ preb,
    const float* __restrict__ qw, const float* __restrict__ pw1,
    const float* __restrict__ pb1, const float* __restrict__ pw2,
    const float* __restrict__ pb2, float* __restrict__ out) {
  const int lane = threadIdx.x & 63;
  const int gid = (blockIdx.x * 256 + threadIdx.x) >> 6;
  if (gid >= NG) return;
  const float cnt = fmaxf(gcnt[gid], 1.f);
  const float gv = g[gid * 64 + lane] / cnt;
  float qin[4];
#pragma unroll
  for (int q = 0; q < 4; ++q)
    qin[q] = wave_sum(gv * prew[lane * 4 + q]) + preb[q];
  // 4-qubit statevector; reference bit order: qubit q <-> bit (3-q)
  float sr[16], si[16];
#pragma unroll
  for (int i = 0; i < 16; ++i) { sr[i] = 0.f; si[i] = 0.f; }
  sr[0] = 1.f;
#pragma unroll
  for (int q = 0; q < 4; ++q) {  // RX(qin[q])
    const int mask = 8 >> q;
    float s, c;
    __sincosf(qin[q] * 0.5f, &s, &c);
#pragma unroll
    for (int i = 0; i < 16; ++i)
      if (!(i & mask)) {
        const int j = i | mask;
        const float ar = sr[i], ai = si[i], br = sr[j], bi = si[j];
        sr[i] = c * ar + s * bi; si[i] = c * ai - s * br;
        sr[j] = c * br + s * ai; si[j] = c * bi - s * ar;
      }
  }
#pragma unroll
  for (int l = 0; l < 2; ++l) {
#pragma unroll
    for (int q = 0; q < 4; ++q) {  // RY(qw[l][q])
      const int mask = 8 >> q;
      float s, c;
      __sincosf(qw[l * 4 + q] * 0.5f, &s, &c);
#pragma unroll
      for (int i = 0; i < 16; ++i)
        if (!(i & mask)) {
          const int j = i | mask;
          const float ar = sr[i], ai = si[i], br = sr[j], bi = si[j];
          sr[i] = c * ar - s * br; si[i] = c * ai - s * bi;
          sr[j] = s * ar + c * br; si[j] = s * ai + c * bi;
        }
    }
#pragma unroll
    for (int q = 0; q < 4; ++q) {  // CNOT q -> (q+1)%4
      const int mc = 8 >> q;
      const int mt = 8 >> ((q + 1) & 3);
#pragma unroll
      for (int i = 0; i < 16; ++i)
        if ((i & mc) && !(i & mt)) {
          const int j = i | mt;
          float t = sr[i]; sr[i] = sr[j]; sr[j] = t;
          t = si[i]; si[i] = si[j]; si[j] = t;
        }
    }
  }
  float qo[4] = {0.f, 0.f, 0.f, 0.f};
#pragma unroll
  for (int i = 0; i < 16; ++i) {
    const float p = sr[i] * sr[i] + si[i] * si[i];
#pragma unroll
    for (int q = 0; q < 4; ++q) qo[q] += ((i >> (3 - q)) & 1) ? -p : p;
  }
  float t = pb1[lane];
#pragma unroll
  for (int q = 0; q < 4; ++q) t += qo[q] * pw1[q * 64 + lane];
  const float r = wave_sum(silu_f(t) * pw2[lane]);
  if (lane == 0) out[gid] = r + pb2[0];
}

extern "C" void kernel_launch(void* const* d_in, const int* in_sizes, int n_in,
                              void* d_out, int out_size, void* d_ws, size_t ws_size,
                              hipStream_t stream) {
  (void)in_sizes; (void)n_in; (void)out_size; (void)ws_size;
  const int*   nt    = (const int*)d_in[0];
  const float* pos0  = (const float*)d_in[1];
  const int*   ei    = (const int*)d_in[2];
  const float* eattr = (const float*)d_in[3];
  const int*   batch = (const int*)d_in[4];
  const float* emb   = (const float*)d_in[5];
  const float* ew1   = (const float*)d_in[6];
  const float* eb1   = (const float*)d_in[7];
  const float* ew2   = (const float*)d_in[8];
  const float* eb2   = (const float*)d_in[9];
  const float* cw1   = (const float*)d_in[10];
  const float* cb1   = (const float*)d_in[11];
  const float* cw2   = (const float*)d_in[12];
  const float* cb2   = (const float*)d_in[13];
  const float* nw1   = (const float*)d_in[14];
  const float* nb1   = (const float*)d_in[15];
  const float* nw2   = (const float*)d_in[16];
  const float* nb2   = (const float*)d_in[17];
  const float* prew  = (const float*)d_in[18];
  const float* preb  = (const float*)d_in[19];
  const float* qw    = (const float*)d_in[20];
  const float* pw1   = (const float*)d_in[21];
  const float* pb1   = (const float*)d_in[22];
  const float* pw2   = (const float*)d_in[23];
  const float* pb2   = (const float*)d_in[24];
  float* out = (float*)d_out;

  float* ws   = (float*)d_ws;
  float* h    = ws;               // NN*64
  float* pos  = h + NN * 64;      // NN*3
  float* posd = pos + NN * 3;     // NN*3
  float* agg  = posd + NN * 3;    // NN*64
  float* deg  = agg + NN * 64;    // NN
  float* g    = deg + NN;         // NG*64
  float* gcnt = g + NG * 64;      // NG

  k_init_h<<<(NN * 64 + 255) / 256, 256, 0, stream>>>(nt, emb, h);
  k_prep<<<(NN * 3 + 255) / 256, 256, 0, stream>>>(pos0, pos, deg, g, gcnt);
  k_hist<<<(NE + 255) / 256, 256, 0, stream>>>(ei, deg);
  k_cnt<<<(NN + 255) / 256, 256, 0, stream>>>(batch, deg, gcnt);
  for (int l = 0; l < NL; ++l) {
    k_zero<<<(NN * 67 + 255) / 256, 256, 0, stream>>>(agg, posd);
    k_edge<<<768, 256, 0, stream>>>(h, pos, ei, eattr,
        ew1 + l * 133 * 64, eb1 + l * 64, ew2 + l * 64 * 64, eb2 + l * 64,
        cw1 + l * 64 * 64, cb1 + l * 64, cw2 + l * 64, cb2 + l, agg, posd);
    k_pos<<<(NN * 3 + 255) / 256, 256, 0, stream>>>(pos, posd, deg);
    k_node<<<512, 256, 0, stream>>>(h, agg, nw1 + l * 128 * 64, nb1 + l * 64,
                                    nw2 + l * 64 * 64, nb2 + l * 64);
  }
  k_pool<<<(NN * 64 + 255) / 256, 256, 0, stream>>>(h, batch, g);
  k_final<<<(NG * 64 + 255) / 256, 256, 0, stream>>>(g, gcnt, prew, preb, qw,
                                                     pw1, pb1, pw2, pb2, out);
}

// Round 2
// 1865.578 us; speedup vs baseline: 3.2147x; 3.2147x over previous
//
#include <hip/hip_runtime.h>

#define NN 50000
#define NE 800000
#define NG 128
#define NL 3

typedef __attribute__((ext_vector_type(8))) short short8;
typedef __attribute__((ext_vector_type(4))) float f32x4;
typedef __attribute__((ext_vector_type(4))) int i32x4;

union FragU { i32x4 i; short8 s; };

__device__ __forceinline__ float silu_f(float x) { return x / (1.f + __expf(-x)); }
__device__ __forceinline__ float rdl(float v, int l) {
  return __int_as_float(__builtin_amdgcn_readlane(__float_as_int(v), l));
}
__device__ __forceinline__ float wave_sum(float v) {
#pragma unroll
  for (int m = 1; m < 64; m <<= 1) v += __shfl_xor(v, m, 64);
  return v;
}

__device__ __forceinline__ unsigned f2u(float x) { return __float_as_uint(x); }
__device__ __forceinline__ float hi_part(float x) {
  return __uint_as_float(f2u(x) & 0xffff0000u);
}
// pack two fp32 -> (bf16,bf16) dword via truncation; e0 in low half
__device__ __forceinline__ unsigned pk_hi(float e0, float e1) {
  return __builtin_amdgcn_perm(f2u(e1), f2u(e0), 0x07060302u);
}
// fp32 -> one dword: hi-bf16 bits in high half, lo-bf16 (bf16 of residual) in low half
__device__ __forceinline__ unsigned pk_hilo(float x) {
  unsigned h = f2u(x) & 0xffff0000u;
  float r = x - __uint_as_float(h);
  return h | (f2u(r) >> 16);
}

__device__ __forceinline__ f32x4 mfma16(i32x4 a, i32x4 b, f32x4 c) {
  FragU ua, ub; ua.i = a; ub.i = b;
  return __builtin_amdgcn_mfma_f32_16x16x32_bf16(ua.s, ub.s, c, 0, 0, 0);
}

// split 8 fp32 into hi/lo bf16x8 fragments (A-frag element order: k ascending)
__device__ __forceinline__ void split8(const float* x, i32x4& fh, i32x4& fl) {
#pragma unroll
  for (int i = 0; i < 4; ++i) {
    const float a = x[2 * i], b = x[2 * i + 1];
    fh[i] = (int)pk_hi(a, b);
    fl[i] = (int)pk_hi(a - hi_part(a), b - hi_part(b));
  }
}

// build B-frag (hi/lo) for W[k][n] tile: rows k0..k0+31, cols c0..c0+15 (ld=64)
__device__ __forceinline__ void wfrag(const float* __restrict__ W, int nrows, int k0,
                                      int c0, int lane, i32x4& fh, i32x4& fl) {
  const int kb = k0 + ((lane >> 4) << 3);
  const int n = c0 + (lane & 15);
  float x[8];
#pragma unroll
  for (int j = 0; j < 8; ++j) {
    const int k = kb + j;
    x[j] = (k < nrows) ? W[k * 64 + n] : 0.f;
  }
  split8(x, fh, fl);
}

// unpack 8 staged dwords (hi|lo) into hi/lo A-frags
__device__ __forceinline__ void unpack8(const unsigned* d, i32x4& fh, i32x4& fl) {
#pragma unroll
  for (int i = 0; i < 4; ++i) {
    fh[i] = (int)__builtin_amdgcn_perm(d[2 * i + 1], d[2 * i], 0x07060302u);
    fl[i] = (int)__builtin_amdgcn_perm(d[2 * i + 1], d[2 * i], 0x05040100u);
  }
}

// ---------------- init / small kernels ----------------
__global__ __launch_bounds__(256) void k_init_h(const int* __restrict__ nt,
                                                const float* __restrict__ emb,
                                                float* __restrict__ h) {
  int idx = blockIdx.x * 256 + threadIdx.x;
  if (idx < NN * 64) h[idx] = emb[nt[idx >> 6] * 64 + (idx & 63)];
}

__global__ __launch_bounds__(256) void k_prep(const float* __restrict__ pos_in,
                                              float* __restrict__ pos,
                                              float* __restrict__ deg,
                                              float* __restrict__ g,
                                              float* __restrict__ gcnt) {
  int idx = blockIdx.x * 256 + threadIdx.x;
  if (idx < NN * 3) pos[idx] = pos_in[idx];
  if (idx < NN) deg[idx] = 0.f;
  if (idx < NG * 64) g[idx] = 0.f;
  if (idx < NG) gcnt[idx] = 0.f;
}

__global__ __launch_bounds__(256) void k_hist(const int* __restrict__ ei,
                                              float* __restrict__ deg) {
  int e = blockIdx.x * 256 + threadIdx.x;
  if (e < NE) atomicAdd(&deg[ei[NE + e]], 1.f);
}

__global__ __launch_bounds__(256) void k_cnt(const int* __restrict__ batch,
                                             float* __restrict__ deg,
                                             float* __restrict__ gcnt) {
  int i = blockIdx.x * 256 + threadIdx.x;
  if (i < NN) {
    deg[i] = fmaxf(deg[i], 1.f);
    atomicAdd(&gcnt[batch[i]], 1.f);
  }
}

__global__ __launch_bounds__(256) void k_zero(float* __restrict__ agg,
                                              float* __restrict__ posd) {
  int idx = blockIdx.x * 256 + threadIdx.x;
  if (idx < NN * 64) agg[idx] = 0.f;
  else if (idx < NN * 64 + NN * 3) posd[idx - NN * 64] = 0.f;
}

__global__ __launch_bounds__(256) void k_pos(float* __restrict__ pos,
                                             const float* __restrict__ posd,
                                             const float* __restrict__ deg) {
  int idx = blockIdx.x * 256 + threadIdx.x;
  if (idx < NN * 3) pos[idx] += posd[idx] / deg[idx / 3];
}

__global__ __launch_bounds__(256) void k_pool(const float* __restrict__ h,
                                              const int* __restrict__ batch,
                                              float* __restrict__ g) {
  int idx = blockIdx.x * 256 + threadIdx.x;
  if (idx < NN * 64) atomicAdd(&g[batch[idx >> 6] * 64 + (idx & 63)], h[idx]);
}

// ---------------- edge message kernel (split-bf16 MFMA) ----------------
// block = 4 waves; each iteration processes 16 edges; wave w owns output cols
// [16w, 16w+16). Weights live in VGPRs (built once). m1/mm transposed through
// LDS as packed (hi|lo) dwords. Row stride 68 dwords: 16B-aligned b128 reads,
// worst 2-way bank aliasing (free).
__global__ __launch_bounds__(256, 2) void k_edge(
    const float* __restrict__ h, const float* __restrict__ pos,
    const int* __restrict__ ei, const float* __restrict__ eattr,
    const float* __restrict__ W1, const float* __restrict__ B1,
    const float* __restrict__ W2, const float* __restrict__ B2,
    const float* __restrict__ C1, const float* __restrict__ CB1,
    const float* __restrict__ C2, const float* __restrict__ CB2,
    float* __restrict__ agg, float* __restrict__ posd) {
  __shared__ unsigned buf1[16 * 68];
  __shared__ unsigned buf2[16 * 68];
  __shared__ float cpart[4][16];

  const int lane = threadIdx.x & 63;
  const int w = threadIdx.x >> 6;
  const int m = lane & 15;
  const int quad = lane >> 4;
  const int col = 16 * w + m;

  // register-resident weight fragments for this wave's n-slice
  i32x4 w1h[5], w1l[5], w2h[2], w2l[2], c1h[2], c1l[2];
#pragma unroll
  for (int s = 0; s < 5; ++s) wfrag(W1, 133, 32 * s, 16 * w, lane, w1h[s], w1l[s]);
#pragma unroll
  for (int s = 0; s < 2; ++s) wfrag(W2, 64, 32 * s, 16 * w, lane, w2h[s], w2l[s]);
#pragma unroll
  for (int s = 0; s < 2; ++s) wfrag(C1, 64, 32 * s, 16 * w, lane, c1h[s], c1l[s]);

  const float eb1v = B1[col], eb2v = B2[col], cb1v = CB1[col];
  const float cw2v = C2[col], cb2v = CB2[0];

  const int ngroups = NE / 16;
  for (int g = blockIdx.x; g < ngroups; g += gridDim.x) {
    const int e0 = g * 16;
    const int esrc = ei[e0 + m];
    const int edst = ei[NE + e0 + m];

    // per-edge tail data (quad-0 lanes: lane == edge index within group)
    float d2v = 0.f, ea0 = 0.f, ea1 = 0.f, ea2 = 0.f, ea3 = 0.f;
    float rx = 0.f, ry = 0.f, rz = 0.f;
    if (lane < 16) {
      const int s_ = ei[e0 + lane], d_ = ei[NE + e0 + lane];
      rx = pos[d_ * 3 + 0] - pos[s_ * 3 + 0];
      ry = pos[d_ * 3 + 1] - pos[s_ * 3 + 1];
      rz = pos[d_ * 3 + 2] - pos[s_ * 3 + 2];
      d2v = rx * rx + ry * ry + rz * rz;
      const float4 ea = *(const float4*)(eattr + 4 * (e0 + lane));
      ea0 = ea.x; ea1 = ea.y; ea2 = ea.z; ea3 = ea.w;
    }

    // ---- GEMV1: m_in[16 x 160] @ W1[160 x 64] (this wave: 16 cols) ----
    f32x4 acc = {eb1v, eb1v, eb1v, eb1v};
#pragma unroll
    for (int s = 0; s < 4; ++s) {
      const float* base = h + (size_t)(s < 2 ? edst : esrc) * 64 + (s & 1) * 32 + quad * 8;
      const float4 xa = *(const float4*)base;
      const float4 xb = *(const float4*)(base + 4);
      float x[8] = {xa.x, xa.y, xa.z, xa.w, xb.x, xb.y, xb.z, xb.w};
      i32x4 ah, al;
      split8(x, ah, al);
      acc = mfma16(ah, w1h[s], acc);
      acc = mfma16(ah, w1l[s], acc);
      acc = mfma16(al, w1h[s], acc);
    }
    {  // tail k-step: cols 128..159 = [d2, ea0..3, 0...]; quads 1-3 all zero
      float x[8] = {d2v, ea0, ea1, ea2, ea3, 0.f, 0.f, 0.f};
      i32x4 ah, al;
      split8(x, ah, al);
      acc = mfma16(ah, w1h[4], acc);
      acc = mfma16(ah, w1l[4], acc);
      acc = mfma16(al, w1h[4], acc);
    }
#pragma unroll
    for (int r = 0; r < 4; ++r)
      buf1[(quad * 4 + r) * 68 + col] = pk_hilo(silu_f(acc[r]));
    __syncthreads();

    // ---- GEMV2: m1[16 x 64] @ W2[64 x 64] ----
    f32x4 acc2 = {eb2v, eb2v, eb2v, eb2v};
#pragma unroll
    for (int s = 0; s < 2; ++s) {
      unsigned d[8];
#pragma unroll
      for (int j = 0; j < 8; ++j) d[j] = buf1[m * 68 + 32 * s + quad * 8 + j];
      i32x4 ah, al;
      unpack8(d, ah, al);
      acc2 = mfma16(ah, w2h[s], acc2);
      acc2 = mfma16(ah, w2l[s], acc2);
      acc2 = mfma16(al, w2h[s], acc2);
    }
    float mmv[4];
#pragma unroll
    for (int r = 0; r < 4; ++r) mmv[r] = silu_f(acc2[r]);
#pragma unroll
    for (int r = 0; r < 4; ++r) {
      buf2[(quad * 4 + r) * 68 + col] = pk_hilo(mmv[r]);
      const int rdst = ei[NE + e0 + quad * 4 + r];
      atomicAdd(&agg[(size_t)rdst * 64 + col], mmv[r]);
    }
    __syncthreads();

    // ---- coord MLP: a3 = mm @ C1 + cb1; c = sum(silu(a3)*cw2) + cb2 ----
    f32x4 acc3 = {cb1v, cb1v, cb1v, cb1v};
#pragma unroll
    for (int s = 0; s < 2; ++s) {
      unsigned d[8];
#pragma unroll
      for (int j = 0; j < 8; ++j) d[j] = buf2[m * 68 + 32 * s + quad * 8 + j];
      i32x4 ah, al;
      unpack8(d, ah, al);
      acc3 = mfma16(ah, c1h[s], acc3);
      acc3 = mfma16(ah, c1l[s], acc3);
      acc3 = mfma16(al, c1h[s], acc3);
    }
    float tr[4];
#pragma unroll
    for (int r = 0; r < 4; ++r) tr[r] = silu_f(acc3[r]) * cw2v;
#pragma unroll
    for (int mask = 1; mask < 16; mask <<= 1)
#pragma unroll
      for (int r = 0; r < 4; ++r) tr[r] += __shfl_xor(tr[r], mask, 64);
    if (m == 0)
#pragma unroll
      for (int r = 0; r < 4; ++r) cpart[w][quad * 4 + r] = tr[r];
    __syncthreads();

    if (w == 0 && lane < 16) {
      const float cv = cpart[0][lane] + cpart[1][lane] + cpart[2][lane] +
                       cpart[3][lane] + cb2v;
      const int d_ = ei[NE + e0 + lane];
      atomicAdd(&posd[d_ * 3 + 0], rx * cv);
      atomicAdd(&posd[d_ * 3 + 1], ry * cv);
      atomicAdd(&posd[d_ * 3 + 2], rz * cv);
    }
  }
}

// ---------------- node update kernel ----------------
__global__ __launch_bounds__(256) void k_node(
    float* __restrict__ h, const float* __restrict__ agg,
    const float* __restrict__ W1, const float* __restrict__ B1,
    const float* __restrict__ W2, const float* __restrict__ B2) {
  __shared__ float sW1[128 * 64];
  __shared__ float sW2[64 * 64];
  for (int i = threadIdx.x; i < 128 * 64; i += 256) sW1[i] = W1[i];
  for (int i = threadIdx.x; i < 64 * 64; i += 256) sW2[i] = W2[i];
  __syncthreads();
  const int lane = threadIdx.x & 63;
  const float nb1 = B1[lane], nb2 = B2[lane];
  const int wid = (blockIdx.x * 256 + threadIdx.x) >> 6;
  const int nw = (gridDim.x * 256) >> 6;
  for (int n = wid; n < NN; n += nw) {
    const float hj = h[n * 64 + lane];
    const float aj = agg[n * 64 + lane];
    float a1 = nb1;
#pragma unroll
    for (int k = 0; k < 64; ++k) a1 += rdl(hj, k) * sW1[k * 64 + lane];
#pragma unroll
    for (int k = 0; k < 64; ++k) a1 += rdl(aj, k) * sW1[(64 + k) * 64 + lane];
    const float u = silu_f(a1);
    float a2 = nb2;
#pragma unroll
    for (int k = 0; k < 64; ++k) a2 += rdl(u, k) * sW2[k * 64 + lane];
    h[n * 64 + lane] = hj + a2;
  }
}

// ---------------- pooled head: q-circuit + MLP ----------------
__global__ __launch_bounds__(256) void k_final(
    const float* __restrict__ g, const float* __restrict__ gcnt,
    const float* __restrict__ prew, const float* __restrict__ preb,
    const float* __restrict__ qw, const float* __restrict__ pw1,
    const float* __restrict__ pb1, const float* __restrict__ pw2,
    const float* __restrict__ pb2, float* __restrict__ out) {
  const int lane = threadIdx.x & 63;
  const int gid = (blockIdx.x * 256 + threadIdx.x) >> 6;
  if (gid >= NG) return;
  const float cnt = fmaxf(gcnt[gid], 1.f);
  const float gv = g[gid * 64 + lane] / cnt;
  float qin[4];
#pragma unroll
  for (int q = 0; q < 4; ++q)
    qin[q] = wave_sum(gv * prew[lane * 4 + q]) + preb[q];
  float sr[16], si[16];
#pragma unroll
  for (int i = 0; i < 16; ++i) { sr[i] = 0.f; si[i] = 0.f; }
  sr[0] = 1.f;
#pragma unroll
  for (int q = 0; q < 4; ++q) {  // RX(qin[q])
    const int mask = 8 >> q;
    float s, c;
    __sincosf(qin[q] * 0.5f, &s, &c);
#pragma unroll
    for (int i = 0; i < 16; ++i)
      if (!(i & mask)) {
        const int j = i | mask;
        const float ar = sr[i], ai = si[i], br = sr[j], bi = si[j];
        sr[i] = c * ar + s * bi; si[i] = c * ai - s * br;
        sr[j] = c * br + s * ai; si[j] = c * bi - s * ar;
      }
  }
#pragma unroll
  for (int l = 0; l < 2; ++l) {
#pragma unroll
    for (int q = 0; q < 4; ++q) {  // RY(qw[l][q])
      const int mask = 8 >> q;
      float s, c;
      __sincosf(qw[l * 4 + q] * 0.5f, &s, &c);
#pragma unroll
      for (int i = 0; i < 16; ++i)
        if (!(i & mask)) {
          const int j = i | mask;
          const float ar = sr[i], ai = si[i], br = sr[j], bi = si[j];
          sr[i] = c * ar - s * br; si[i] = c * ai - s * bi;
          sr[j] = s * ar + c * br; si[j] = s * ai + c * bi;
        }
    }
#pragma unroll
    for (int q = 0; q < 4; ++q) {  // CNOT q -> (q+1)%4
      const int mc = 8 >> q;
      const int mt = 8 >> ((q + 1) & 3);
#pragma unroll
      for (int i = 0; i < 16; ++i)
        if ((i & mc) && !(i & mt)) {
          const int j = i | mt;
          float t = sr[i]; sr[i] = sr[j]; sr[j] = t;
          t = si[i]; si[i] = si[j]; si[j] = t;
        }
    }
  }
  float qo[4] = {0.f, 0.f, 0.f, 0.f};
#pragma unroll
  for (int i = 0; i < 16; ++i) {
    const float p = sr[i] * sr[i] + si[i] * si[i];
#pragma unroll
    for (int q = 0; q < 4; ++q) qo[q] += ((i >> (3 - q)) & 1) ? -p : p;
  }
  float t = pb1[lane];
#pragma unroll
  for (int q = 0; q < 4; ++q) t += qo[q] * pw1[q * 64 + lane];
  const float r = wave_sum(silu_f(t) * pw2[lane]);
  if (lane == 0) out[gid] = r + pb2[0];
}

extern "C" void kernel_launch(void* const* d_in, const int* in_sizes, int n_in,
                              void* d_out, int out_size, void* d_ws, size_t ws_size,
                              hipStream_t stream) {
  (void)in_sizes; (void)n_in; (void)out_size; (void)ws_size;
  const int*   nt    = (const int*)d_in[0];
  const float* pos0  = (const float*)d_in[1];
  const int*   ei    = (const int*)d_in[2];
  const float* eattr = (const float*)d_in[3];
  const int*   batch = (const int*)d_in[4];
  const float* emb   = (const float*)d_in[5];
  const float* ew1   = (const float*)d_in[6];
  const float* eb1   = (const float*)d_in[7];
  const float* ew2   = (const float*)d_in[8];
  const float* eb2   = (const float*)d_in[9];
  const float* cw1   = (const float*)d_in[10];
  const float* cb1   = (const float*)d_in[11];
  const float* cw2   = (const float*)d_in[12];
  const float* cb2   = (const float*)d_in[13];
  const float* nw1   = (const float*)d_in[14];
  const float* nb1   = (const float*)d_in[15];
  const float* nw2   = (const float*)d_in[16];
  const float* nb2   = (const float*)d_in[17];
  const float* prew  = (const float*)d_in[18];
  const float* preb  = (const float*)d_in[19];
  const float* qw    = (const float*)d_in[20];
  const float* pw1   = (const float*)d_in[21];
  const float* pb1   = (const float*)d_in[22];
  const float* pw2   = (const float*)d_in[23];
  const float* pb2   = (const float*)d_in[24];
  float* out = (float*)d_out;

  float* ws   = (float*)d_ws;
  float* h    = ws;               // NN*64
  float* pos  = h + NN * 64;      // NN*3
  float* posd = pos + NN * 3;     // NN*3
  float* agg  = posd + NN * 3;    // NN*64
  float* deg  = agg + NN * 64;    // NN
  float* g    = deg + NN;         // NG*64
  float* gcnt = g + NG * 64;      // NG

  k_init_h<<<(NN * 64 + 255) / 256, 256, 0, stream>>>(nt, emb, h);
  k_prep<<<(NN * 3 + 255) / 256, 256, 0, stream>>>(pos0, pos, deg, g, gcnt);
  k_hist<<<(NE + 255) / 256, 256, 0, stream>>>(ei, deg);
  k_cnt<<<(NN + 255) / 256, 256, 0, stream>>>(batch, deg, gcnt);
  for (int l = 0; l < NL; ++l) {
    k_zero<<<(NN * 67 + 255) / 256, 256, 0, stream>>>(agg, posd);
    k_edge<<<2048, 256, 0, stream>>>(h, pos, ei, eattr,
        ew1 + l * 133 * 64, eb1 + l * 64, ew2 + l * 64 * 64, eb2 + l * 64,
        cw1 + l * 64 * 64, cb1 + l * 64, cw2 + l * 64, cb2 + l, agg, posd);
    k_pos<<<(NN * 3 + 255) / 256, 256, 0, stream>>>(pos, posd, deg);
    k_node<<<512, 256, 0, stream>>>(h, agg, nw1 + l * 128 * 64, nb1 + l * 64,
                                    nw2 + l * 64 * 64, nb2 + l * 64);
  }
  k_pool<<<(NN * 64 + 255) / 256, 256, 0, stream>>>(h, batch, g);
  k_final<<<(NG * 64 + 255) / 256, 256, 0, stream>>>(g, gcnt, prew, preb, qw,
                                                     pw1, pb1, pw2, pb2, out);
}